// Round 1
// baseline (158.951 us; speedup 1.0000x reference)
//
#include <hip/hip_runtime.h>

// CRS rate-and-state model: per-row sequential recurrence parallelized via
// Mobius-transform composition. Each step t maps R -> (et*R)/(1 + c*R) with
// c = (eta/sd)*(et-1). Maps [[a,0],[c,1]] are closed under composition, so we
// wave-scan (A,C) pairs: one wave per row, 64 lanes x 4 steps = 256-step tiles.

#define C_TNSR  0.001f
#define C_TSSR  0.002f
#define C_SIGMA 50.0f
#define C_BIOT  0.3f
#define C_R0    0.0001f
#define C_N0    0.0001f

constexpr int B = 8192;
constexpr int T = 4096;
constexpr int TILE = 256;   // timesteps per wave-iteration (64 lanes x 4)

typedef float f4 __attribute__((ext_vector_type(4)));

__global__ __launch_bounds__(256, 4)
void crs_scan_kernel(const float* __restrict__ params,
                     const float* __restrict__ p,
                     const float* __restrict__ dpdt,
                     const float* __restrict__ dtv,
                     float* __restrict__ Rt,
                     float* __restrict__ Nt)
{
    const int lane = threadIdx.x & 63;
    const int wave = (int)((blockIdx.x * blockDim.x + threadIdx.x) >> 6);
    if (wave >= B) return;
    const int b = wave;

    const float mu  = params[b * 3 + 0];
    const float rc  = params[b * 3 + 1];
    const float rf  = params[b * 3 + 2];
    const float eta = 1.0f / rf;

    const float* __restrict__ prow = p    + (size_t)b * T;
    const float* __restrict__ drow = dpdt + (size_t)b * T;
    const float* __restrict__ trow = dtv  + (size_t)b * T;
    float* __restrict__ Rrow = Rt + (size_t)b * (T + 1) + 1;
    float* __restrict__ Nrow = Nt + (size_t)b * (T + 1) + 1;

    if (lane == 0) {
        Rrow[-1] = C_R0;   // Rt[b,0]
        Nrow[-1] = C_N0;   // Nt[b,0]
    }

    float Rc = C_R0;   // running R carry (R after last processed step)
    float Nc = C_N0;   // running Nt carry (cumsum incl. N0)

    for (int t0 = 0; t0 < T; t0 += TILE) {
        const int off = t0 + 4 * lane;
        // coalesced 16B/lane loads (base is 16B aligned: b*T, t0, 4*lane all x4 floats)
        f4 pv = *(const f4*)(prow + off);
        f4 dv = *(const f4*)(drow + off);
        f4 tv = *(const f4*)(trow + off);

        float et[4], cc[4], kk[4];
        float A = 1.0f, C = 0.0f;
#pragma unroll
        for (int j = 0; j < 4; ++j) {
            float sd   = C_TSSR - mu * (C_TNSR - dv[j]);
            float asig = rc * (C_SIGMA - C_BIOT * pv[j]);
            float e    = __expf(__fdividef(sd * tv[j], asig));
            float c    = __fdividef(eta * (e - 1.0f), sd);
            et[j] = e;
            cc[j] = c;
            kk[j] = asig * rf;           // asig/eta
            C = fmaf(c, A, C);           // compose step j after (A,C)
            A = A * e;
        }

        // wave-inclusive scan of Mobius pairs (A,C); combine(cur ∘ prev):
        // A = A*Ap ; C = C*Ap + Cp
#pragma unroll
        for (int o = 1; o < 64; o <<= 1) {
            float Ap = __shfl_up(A, (unsigned)o, 64);
            float Cp = __shfl_up(C, (unsigned)o, 64);
            if (lane >= o) {
                C = fmaf(C, Ap, Cp);
                A = A * Ap;
            }
        }
        // exclusive prefix for this lane's 4-step segment
        float Ae = __shfl_up(A, 1u, 64);
        float Ce = __shfl_up(C, 1u, 64);
        if (lane == 0) { Ae = 1.0f; Ce = 0.0f; }

        // R entering this lane's segment
        float Rp = __fdividef(Ae * Rc, fmaf(Ce, Rc, 1.0f));

        float rr[4], nn[4];
        float ns = 0.0f;
#pragma unroll
        for (int j = 0; j < 4; ++j) {
            float den = fmaf(cc[j], Rp, 1.0f);        // == 1 - (eta*R/sd)*(1-et)
            float n   = kk[j] * __logf(den);
            Rp = __fdividef(Rp * et[j], den);
            rr[j] = Rp;
            ns += n;
            nn[j] = ns;                                // local inclusive cumsum
        }

        // wave-inclusive prefix sum of per-lane N totals
        float S = ns;
#pragma unroll
        for (int o = 1; o < 64; o <<= 1) {
            float Sp = __shfl_up(S, (unsigned)o, 64);
            if (lane >= o) S += Sp;
        }
        float base = Nc + (S - ns);   // carry + exclusive prefix

#pragma unroll
        for (int j = 0; j < 4; ++j) {
            Rrow[off + j] = rr[j];
            Nrow[off + j] = base + nn[j];
        }

        // carries from lane 63
        Rc = __shfl(Rp, 63, 64);
        Nc = Nc + __shfl(S, 63, 64);
    }
}

extern "C" void kernel_launch(void* const* d_in, const int* in_sizes, int n_in,
                              void* d_out, int out_size, void* d_ws, size_t ws_size,
                              hipStream_t stream)
{
    const float* params = (const float*)d_in[0];
    const float* p      = (const float*)d_in[1];
    const float* dpdt   = (const float*)d_in[2];
    const float* dtv    = (const float*)d_in[3];

    float* Rt = (float*)d_out;                       // B*(T+1)
    float* Nt = (float*)d_out + (size_t)B * (T + 1); // B*(T+1)

    const int block = 256;                 // 4 waves = 4 rows per block
    const int grid  = (B * 64) / block;    // 2048 blocks
    crs_scan_kernel<<<grid, block, 0, stream>>>(params, p, dpdt, dtv, Rt, Nt);
}